// Round 10
// baseline (108.825 us; speedup 1.0000x reference)
//
#include <hip/hip_runtime.h>
#include <math.h>

#define BB 64
#define QQ 600
#define NT 80
#define NC 92
#define SLOTS 10     // ceil(600/64)
#define NTILE 10     // 64-query tiles per batch
#define NTHR 256
#define NWAVE 4
#define MAXROUNDS 16 // Jacobi auction cap
#define STALLCAP 3   // break auction after 3 rounds with no new assignment

// ---------------------------------------------------------------------------
// R24 = R23 (107.6us measured; split kernels won -12us) + dist-form Dijkstra
// drain (textbook lapjv deferred-dual formulation). The old loop paid a
// ~200cy full-width dual-update pass (v_-=d, minv_-=d, u[p]+=d) on EVERY tree
// extension; dist-form keeps minv_ as ABSOLUTE path distance (cand = base +
// (c-u-v), base = d[j0]), leaves u/v untouched mid-loop, and applies the dual
// correction ONCE per augmentation over used columns only:
//   adj = d_final - d[j]; v[j] -= adj; u[p[j]] += adj; u[i] += d_final.
// Algebraically identical to the reference (its minv == our d - delta_sofar;
// argmin invariant under the uniform shift; selection & tie-break preserved);
// fp trajectory differs at ~1e-16 — same measure-zero tie class as R16's
// accepted key maps. Everything else R23-verbatim.
// ---------------------------------------------------------------------------

template <int CTRL>
__device__ __forceinline__ int dppi(int x) {
    return __builtin_amdgcn_update_dpp(x, x, CTRL, 0xF, 0xF, false);
}

// full-wave (64-lane) min of u32: 4x row_ror DPP (VALU) + xor16 swizzle + xor32
__device__ __forceinline__ unsigned wave_min_u32(unsigned x) {
    unsigned y;
    y = (unsigned)dppi<0x121>((int)x); x = x < y ? x : y;   // ror1
    y = (unsigned)dppi<0x122>((int)x); x = x < y ? x : y;   // ror2
    y = (unsigned)dppi<0x124>((int)x); x = x < y ? x : y;   // ror4
    y = (unsigned)dppi<0x128>((int)x); x = x < y ? x : y;   // ror8 -> row(16) min
    y = (unsigned)__builtin_amdgcn_ds_swizzle((int)x, 0x401F); x = x < y ? x : y; // xor16
    y = (unsigned)__shfl_xor((int)x, 32); x = x < y ? x : y;                      // xor32
    return x;
}

// exact 64-lane min of a u64 sortable key, two-phase (hi then lo).
// Returns min key; *winlane = lowest lane holding it (old tie semantics).
__device__ __forceinline__ unsigned long long wave_min_key64(
        unsigned long long key, int* winlane) {
    const unsigned hi = (unsigned)(key >> 32), lo = (unsigned)key;
    const unsigned mhi = wave_min_u32(hi);
    unsigned long long t = __ballot(hi == mhi);
    unsigned mlo;
    if (__popcll(t) > 1) {          // wave-uniform branch (t uniform)
        mlo = wave_min_u32((hi == mhi) ? lo : 0xFFFFFFFFu);
        t = __ballot(hi == mhi && lo == mlo);
    } else {
        mlo = (unsigned)__shfl((int)lo, __builtin_ctzll(t));
    }
    *winlane = __builtin_ctzll(t);
    return ((unsigned long long)mhi << 32) | mlo;
}

// min-value-only variant (no winlane needed)
__device__ __forceinline__ unsigned long long wave_min_key64_val(
        unsigned long long key) {
    const unsigned hi = (unsigned)(key >> 32), lo = (unsigned)key;
    const unsigned mhi = wave_min_u32(hi);
    const unsigned long long t = __ballot(hi == mhi);
    unsigned mlo;
    if (__popcll(t) > 1) mlo = wave_min_u32((hi == mhi) ? lo : 0xFFFFFFFFu);
    else                 mlo = (unsigned)__shfl((int)lo, __builtin_ctzll(t));
    return ((unsigned long long)mhi << 32) | mlo;
}

// order-preserving bijections float<->u32, double<->u64 (no NaNs in data)
__device__ __forceinline__ unsigned f32_key(float f) {
    unsigned b = __float_as_uint(f);
    return b ^ ((unsigned)((int)b >> 31) | 0x80000000u);
}
__device__ __forceinline__ float key_f32(unsigned k) {
    unsigned b = (k & 0x80000000u) ? (k ^ 0x80000000u) : ~k;
    return __uint_as_float(b);
}
__device__ __forceinline__ unsigned long long f64_key(double d) {
    unsigned long long b = (unsigned long long)__double_as_longlong(d);
    return b ^ ((unsigned long long)((long long)b >> 63) | 0x8000000000000000ULL);
}
__device__ __forceinline__ double key_f64(unsigned long long k) {
    unsigned long long b = (k & 0x8000000000000000ULL) ? (k ^ 0x8000000000000000ULL) : ~k;
    return __longlong_as_double((long long)b);
}

// ============================ Kernel A: Phase A =============================
__global__ __launch_bounds__(256) void phasea_kernel(
    const float* __restrict__ logits,   // (B,Q,NC)
    const float* __restrict__ pboxes,   // (B,Q,4)
    const int*   __restrict__ tlabels,  // (B,NT)
    const float* __restrict__ tboxes,   // (B,NT,4)
    float* __restrict__ cost,           // (B,NT,QQ) ws
    float* __restrict__ pm1,            // (B,NT,NTILE) ws
    float* __restrict__ pm2,            // (B,NT,NTILE) ws
    int*   __restrict__ pmj)            // (B,NT,NTILE) ws
{
    __shared__ float tile[64 * 93];
    __shared__ float s_pm[4 * 64], s_ps[4 * 64];
    __shared__ float s_tb[NT * 4];
    __shared__ int   s_tl[NT];

    const int g   = blockIdx.x;
    const int b   = g / NTILE;
    const int tix = g % NTILE;
    const int tid = threadIdx.x;
    const int qq  = tid & 63;
    const int wv  = tid >> 6;           // 0..3

    const int q0 = tix * 64;
    const int nq = min(64, QQ - q0);   // 24 for the last tile
    const float* src = logits + ((size_t)b * QQ + q0) * NC;
    for (int idx = tid; idx < nq * NC; idx += 256) {
        const int r = idx / NC;
        tile[r * 93 + (idx - r * NC)] = src[idx];
    }
    for (int i = tid; i < NT * 4; i += 256) s_tb[i] = tboxes[b * NT * 4 + i];
    for (int i = tid; i < NT;     i += 256) s_tl[i] = tlabels[b * NT + i];
    __syncthreads();

    // 4-way parallel softmax stats; wave w owns cols [w*23, w*23+23).
    {
        const int c0 = wv * 23;
        const float* r = &tile[qq * 93];
        float pm = r[c0];
        #pragma unroll 11
        for (int c = 1; c < 23; ++c) pm = fmaxf(pm, r[c0 + c]);
        s_pm[wv * 64 + qq] = pm;
    }
    __syncthreads();
    {
        const int c0 = wv * 23;
        float* r = &tile[qq * 93];
        const float m = fmaxf(fmaxf(s_pm[qq], s_pm[64 + qq]),
                              fmaxf(s_pm[128 + qq], s_pm[192 + qq]));
        float sum = 0.f;
        #pragma unroll 11
        for (int c = 0; c < 23; ++c) {
            const float e = expf(r[c0 + c] - m);
            r[c0 + c] = e;                  // exp written back into tile
            sum += e;
        }
        s_ps[wv * 64 + qq] = sum;
    }
    __syncthreads();

    const bool valid = qq < nq;
    float px1 = 0.f, py1 = 0.f, px2 = 0.f, py2 = 0.f, pa = 0.f, inv_s = 1.f;
    if (valid) {
        const float* pb = pboxes + ((size_t)b * QQ + q0 + qq) * 4;
        px1 = pb[0]; py1 = pb[1]; px2 = pb[2]; py2 = pb[3];
        pa  = (px2 - px1) * (py2 - py1);
        const float s = (s_ps[qq] + s_ps[64 + qq]) + (s_ps[128 + qq] + s_ps[192 + qq]);
        inv_s = 1.f / s;
    }
    float* crow = cost + (size_t)b * NT * QQ + q0 + qq;

    for (int tt = 0; tt < 20; ++tt) {
        const int t = wv * 20 + tt;
        float costv = INFINITY;
        if (valid) {
            const int lbl = s_tl[t];
            const float cc = -(tile[qq * 93 + lbl] * inv_s);  // exp precomputed
            const float tx1 = s_tb[t*4+0], ty1 = s_tb[t*4+1];
            const float tx2 = s_tb[t*4+2], ty2 = s_tb[t*4+3];
            const float cb = fabsf(px1-tx1) + fabsf(py1-ty1)
                           + fabsf(px2-tx2) + fabsf(py2-ty2);
            const float ta = (tx2 - tx1) * (ty2 - ty1);
            const float iw = fmaxf(fminf(px2, tx2) - fmaxf(px1, tx1), 0.f);
            const float ih = fmaxf(fminf(py2, ty2) - fmaxf(py1, ty1), 0.f);
            const float inter = iw * ih;
            const float uni   = pa + ta - inter;
            const float iou   = inter / uni;
            const float cw = fmaxf(fmaxf(px2, tx2) - fminf(px1, tx1), 0.f);
            const float ch = fmaxf(fmaxf(py2, ty2) - fminf(py1, ty1), 0.f);
            const float ac = cw * ch;
            const float giou = iou - (ac - uni) / ac;
            costv = (1.0f * cc + 5.0f * cb) + 2.0f * (-giou);
            crow[(size_t)t * QQ] = costv;
        }
        // DPP min-reduce on sortable keys + ballot argmin (R16-validated)
        const unsigned key  = f32_key(costv);          // INF for invalid lanes
        const unsigned kmin = wave_min_u32(key);
        const unsigned long long tied = __ballot(key == kmin);
        const int winlane = __builtin_ctzll(tied);
        const unsigned cand = (qq == winlane) ? 0xFFFFFFFFu : key;
        const unsigned k2   = wave_min_u32(cand);      // 2nd-min (dups kept)
        if (qq == 0) {
            const size_t idx = ((size_t)b * NT + t) * NTILE + tix;
            pm1[idx] = key_f32(kmin); pm2[idx] = key_f32(k2);
            pmj[idx] = q0 + winlane;
        }
    }
}

// ============================ Kernel B: solver ==============================
__global__ __launch_bounds__(256) void solver_kernel(
    const float* __restrict__ cost,     // (B,NT,QQ) ws
    const float* __restrict__ pm1,      // (B,NT,NTILE) ws
    const float* __restrict__ pm2,      // (B,NT,NTILE) ws
    const int*   __restrict__ pmj,      // (B,NT,NTILE) ws
    int* __restrict__ rows_out,         // (B,NT)
    int* __restrict__ cols_out)         // (B,NT)
{
    __shared__ double vA[QQ];
    __shared__ double u[NT];
    __shared__ double bidm1[NT], bidm2[NT];
    __shared__ int    bidj[NT], bidver[NT];
    __shared__ int    pA[QQ];
    __shared__ int    verA[QQ];
    __shared__ int    colrow[QQ];
    __shared__ int    assigned[NT];
    __shared__ int    plist[NT];
    __shared__ int    pcnt;
    __shared__ int    wayA[QQ];
    __shared__ int    c4r[NT];
    __shared__ int    djkA[NT];

    const int b   = blockIdx.x;
    const int tid = threadIdx.x;
    const int qq  = tid & 63;
    const int wv  = tid >> 6;           // 0..3
    const float* C = cost + (size_t)b * NT * QQ;

    // ---- init solver state ----
    for (int c = tid; c < QQ; c += NTHR) { pA[c] = -1; verA[c] = 0; vA[c] = 0.0; }
    if (tid < NT) { assigned[tid] = 0; bidver[tid] = 0; }
    __syncthreads();

    // ---- combine tile partials -> full-row bids (R6 verbatim) ----
    if (tid < NT) {
        const int t = tid;
        const float* p1 = pm1 + ((size_t)b * NT + t) * NTILE;
        const float* p2 = pm2 + ((size_t)b * NT + t) * NTILE;
        const int*   pj = pmj + ((size_t)b * NT + t) * NTILE;
        float m1 = INFINITY, m2 = INFINITY; int j1 = QQ;
        for (int k = 0; k < NTILE; ++k) {       // ascending => first-occurrence
            const float a1 = p1[k], a2 = p2[k];
            const int   aj = pj[k];
            if (a1 < m1) { m2 = fminf(m1, a2); m1 = a1; j1 = aj; }
            else         { m2 = fminf(m2, a1); }
        }
        bidm1[t] = (double)m1; bidm2[t] = (double)m2; bidj[t] = j1;
        u[t] = (double)m1;      // feasible: keys only increase afterwards
    }
    __syncthreads();

    // ================= Jacobi parallel auction (R16 structure) =============
    int prev_np = 0x7fffffff, stall = 0;
    for (int round = 0; round < MAXROUNDS; ++round) {
        for (int c = tid; c < QQ; c += NTHR) colrow[c] = 0x7fffffff;
        if (tid == 0) pcnt = 0;
        __syncthreads();
        if (tid < NT && !assigned[tid]) {
            const int j = bidj[tid];
            if (bidver[tid] == verA[j]) atomicMin(&colrow[j], tid);
        }
        __syncthreads();
        if (tid < NT && !assigned[tid]) {
            const int i = tid, j = bidj[i];
            if (bidver[i] == verA[j] && colrow[j] == i) {
                const double m1 = bidm1[i], m2 = bidm2[i];
                const int prev = pA[j];
                pA[j] = i;
                verA[j] = verA[j] + 1;
                vA[j] -= (m2 - m1);          // v only decreases (diff >= 0)
                u[i] = m2;
                assigned[i] = 1;
                if (prev >= 0) assigned[prev] = 0;
            }
        }
        __syncthreads();
        if (tid < NT && !assigned[tid]) { const int k = atomicAdd(&pcnt, 1); plist[k] = tid; }
        __syncthreads();
        const int np = pcnt;
        if (np == 0) break;
        if (np >= prev_np) { if (++stall >= STALLCAP) break; }
        else               { stall = 0; }
        prev_np = np;
        for (int idx = wv; idx < np; idx += NWAVE) {
            const int i = plist[idx];
            const float* rp = C + (size_t)i * QQ;
            float rowv[SLOTS];
            #pragma unroll
            for (int k = 0; k < SLOTS; ++k) { const int c = qq + 64*k; rowv[k] = (c < QQ) ? rp[c] : 0.f; }
            double m1 = INFINITY, m2 = INFINITY; int j1 = QQ;
            #pragma unroll
            for (int k = 0; k < SLOTS; ++k) {
                const int c = qq + 64 * k;
                if (c < QQ) {
                    const double key = (double)rowv[k] - vA[c];
                    if (key < m1)      { m2 = m1; m1 = key; j1 = c; }
                    else if (key < m2) { m2 = key; }
                }
            }
            int winlane;
            const unsigned long long kminv = wave_min_key64(f64_key(m1), &winlane);
            // global 2nd-min = min over (winner's m2, everyone else's m1)
            const unsigned long long c2 = (qq == winlane) ? f64_key(m2) : f64_key(m1);
            const unsigned long long k2minv = wave_min_key64_val(c2);
            const int jwin = __shfl(j1, winlane);
            if (qq == 0) {
                bidm1[i] = key_f64(kminv); bidm2[i] = key_f64(k2minv); bidj[i] = jwin;
                bidver[i] = verA[jwin];
                u[i] = key_f64(kminv);       // feasible forever (v only dec.)
            }
        }
        __syncthreads();
    }

    if (wv != 0) return;   // ============ wave 0 only below; no barriers ====
    const int lane = qq;

    // collect drained rows (uniform control flow)
    int nd = 0;
    for (int i = 0; i < NT; ++i) {
        if (!assigned[i]) { if (lane == 0) djkA[nd] = i; ++nd; }
    }

    double v_[SLOTS], minv_[SLOTS];
    int p_[SLOTS];
    #pragma unroll
    for (int k = 0; k < SLOTS; ++k) {
        const int c = lane + 64 * k;
        v_[k] = (c < QQ) ? vA[c] : 0.0;
        p_[k] = (c < QQ) ? pA[c] : -1;
    }

    // ========== Dijkstra SAP — dist-form, deferred duals (R24) =============
    float rowv[SLOTS];
    for (int ii = 0; ii < nd; ++ii) {
        const int i = djkA[ii];
        #pragma unroll
        for (int k = 0; k < SLOTS; ++k) minv_[k] = INFINITY;
        unsigned usedm = 0;
        int j0 = -1;
        double ui0 = u[i];
        double base = 0.0;      // d[j0]: absolute path distance of tree root
        {
            const float* rp = C + (size_t)i * QQ;
            #pragma unroll
            for (int k = 0; k < SLOTS; ++k) { const int c = lane + 64*k; rowv[k] = (c < QQ) ? rp[c] : 0.f; }
        }
        int j1 = -1, i1;
        double dfin = 0.0;

        for (;;) {
            if (j0 >= 0 && (j0 & 63) == lane) usedm |= 1u << (j0 >> 6);

            double bestv = INFINITY; int bestc = QQ;
            #pragma unroll
            for (int k = 0; k < SLOTS; ++k) {
                const int c = lane + 64 * k;
                if (c < QQ && !((usedm >> k) & 1u)) {
                    // absolute distance: base + reduced edge cost
                    const double cand = base + (((double)rowv[k] - ui0) - v_[k]);
                    if (cand < minv_[k]) { minv_[k] = cand; wayA[c] = j0; }
                    if (minv_[k] < bestv) { bestv = minv_[k]; bestc = c; }
                }
            }
            int winlane;
            const unsigned long long kminv = wave_min_key64(f64_key(bestv), &winlane);
            const double dmin = key_f64(kminv);
            j1 = __shfl(bestc, winlane);

            {   // i1 = p[j1] via register select + shuffle
                const int slot = j1 >> 6, lj = j1 & 63;
                int myp = p_[0];
                #pragma unroll
                for (int k = 1; k < SLOTS; ++k) if (slot == k) myp = p_[k];
                i1 = __shfl(myp, lj);
            }

            if (i1 < 0) { dfin = dmin; break; }

            // next tree row; duals untouched mid-loop (dist-form), so u[i1]
            // is simply its pre-augmentation value.
            ui0 = u[i1];
            base = dmin;
            {
                const float* rp = C + (size_t)i1 * QQ;
                #pragma unroll
                for (int k = 0; k < SLOTS; ++k) { const int c = lane + 64*k; rowv[k] = (c < QQ) ? rp[c] : 0.f; }
            }
            j0 = j1;
        }

        // deferred dual update, ONCE per augmentation (used columns only):
        // v[j] -= (dfin - d[j]); u[p[j]] += (dfin - d[j]); u[i] += dfin.
        // p_ is the pre-augment matching (reference updates u[p[used]] with
        // the old p too); rows are distinct (matching) -> no write conflicts.
        #pragma unroll
        for (int k = 0; k < SLOTS; ++k) {
            const int c = lane + 64 * k;
            if (c < QQ && ((usedm >> k) & 1u)) {
                const double adj = dfin - minv_[k];
                v_[k] -= adj;
                u[p_[k]] += adj;
            }
        }
        if (lane == 0) u[i] += dfin;

        if (lane == 0) {        // augment along way chain
            int jj = j1;
            while (jj >= 0) {
                const int pr = wayA[jj];
                pA[jj] = (pr < 0) ? i : pA[pr];
                jj = pr;
            }
        }
        #pragma unroll
        for (int k = 0; k < SLOTS; ++k) {
            const int c = lane + 64 * k;
            p_[k] = (c < QQ) ? pA[c] : -1;
        }
    }

    // ---- emit in increasing query order (== reference's stable argsort) ----
    #pragma unroll
    for (int k = 0; k < SLOTS; ++k) {
        const int c = lane + 64 * k;
        if (c < QQ) { const int t = pA[c]; if (t >= 0) c4r[t] = c; }
    }
    for (int t = lane; t < NT; t += 64) {
        const int c = c4r[t];
        int rank = 0;
        for (int t2 = 0; t2 < NT; ++t2) rank += (c4r[t2] < c) ? 1 : 0;
        rows_out[b * NT + rank] = c;
        cols_out[b * NT + rank] = t;
    }
}

extern "C" void kernel_launch(void* const* d_in, const int* in_sizes, int n_in,
                              void* d_out, int out_size, void* d_ws, size_t ws_size,
                              hipStream_t stream) {
    (void)in_sizes; (void)n_in; (void)out_size; (void)ws_size;
    const float* logits  = (const float*)d_in[0];
    const float* pboxes  = (const float*)d_in[1];
    const int*   tlabels = (const int*)d_in[2];
    const float* tboxes  = (const float*)d_in[3];
    float* cost = (float*)d_ws;                          // 12,288,000 B
    float* pm1  = cost + (size_t)BB * NT * QQ;           // +204,800 B
    float* pm2  = pm1  + (size_t)BB * NT * NTILE;        // +204,800 B
    int*   pmj  = (int*)(pm2 + (size_t)BB * NT * NTILE); // +204,800 B
    int*   out  = (int*)d_out;

    phasea_kernel<<<dim3(BB * NTILE), NTHR, 0, stream>>>(
        logits, pboxes, tlabels, tboxes, cost, pm1, pm2, pmj);
    solver_kernel<<<dim3(BB), NTHR, 0, stream>>>(
        cost, pm1, pm2, pmj, out, out + BB * NT);
}

// Round 11
// 108.735 us; speedup vs baseline: 1.0008x; 1.0008x over previous
//
#include <hip/hip_runtime.h>
#include <math.h>

#define BB 64
#define QQ 600
#define NT 80
#define NC 92
#define SLOTS 10     // ceil(600/64)
#define NTILE 10     // 64-query tiles per batch
#define NTHR 256
#define NWAVE 4
#define MAXROUNDS 16 // Jacobi auction cap
#define STALLCAP 3   // break auction after 3 rounds with no new assignment

// ---------------------------------------------------------------------------
// R25 = R23 solver VERBATIM (best measured, 107.6us; R24 dist-form reverted,
// null) + Phase A reduction restructure: the 20 t-iterations each paid 2
// dependent wave_min_u32 chains (~200cy) = ~4000cy/wave of reduce. Replace
// with LDS staging (s_scan[4][10][65], +10.4KB -> 37.8KB total; occupancy cap
// 4 blocks/CU >= 2.5 resident, no impact) + 10-lane-parallel serial scans:
// store costv -> barrier -> lanes 0..9 scan 64 values each (~400cy for all
// 10 t's at once) -> barrier, two halves. 65-pitch = conflict-free (bank =
// (tt+j)%32). Tie semantics preserved: ascending scan = first-occurrence
// argmin; duplicate-min counts toward 2nd-min (same as DPP+ballot path).
// Drain post-mortem (R20/R21/R24 all null): per-iteration chain components
// mutually overlap; contested rows are L1-resident; drain work stopped.
// ---------------------------------------------------------------------------

template <int CTRL>
__device__ __forceinline__ int dppi(int x) {
    return __builtin_amdgcn_update_dpp(x, x, CTRL, 0xF, 0xF, false);
}

// full-wave (64-lane) min of u32: 4x row_ror DPP (VALU) + xor16 swizzle + xor32
__device__ __forceinline__ unsigned wave_min_u32(unsigned x) {
    unsigned y;
    y = (unsigned)dppi<0x121>((int)x); x = x < y ? x : y;   // ror1
    y = (unsigned)dppi<0x122>((int)x); x = x < y ? x : y;   // ror2
    y = (unsigned)dppi<0x124>((int)x); x = x < y ? x : y;   // ror4
    y = (unsigned)dppi<0x128>((int)x); x = x < y ? x : y;   // ror8 -> row(16) min
    y = (unsigned)__builtin_amdgcn_ds_swizzle((int)x, 0x401F); x = x < y ? x : y; // xor16
    y = (unsigned)__shfl_xor((int)x, 32); x = x < y ? x : y;                      // xor32
    return x;
}

// exact 64-lane min of a u64 sortable key, two-phase (hi then lo).
// Returns min key; *winlane = lowest lane holding it (old tie semantics).
__device__ __forceinline__ unsigned long long wave_min_key64(
        unsigned long long key, int* winlane) {
    const unsigned hi = (unsigned)(key >> 32), lo = (unsigned)key;
    const unsigned mhi = wave_min_u32(hi);
    unsigned long long t = __ballot(hi == mhi);
    unsigned mlo;
    if (__popcll(t) > 1) {          // wave-uniform branch (t uniform)
        mlo = wave_min_u32((hi == mhi) ? lo : 0xFFFFFFFFu);
        t = __ballot(hi == mhi && lo == mlo);
    } else {
        mlo = (unsigned)__shfl((int)lo, __builtin_ctzll(t));
    }
    *winlane = __builtin_ctzll(t);
    return ((unsigned long long)mhi << 32) | mlo;
}

// min-value-only variant (no winlane needed)
__device__ __forceinline__ unsigned long long wave_min_key64_val(
        unsigned long long key) {
    const unsigned hi = (unsigned)(key >> 32), lo = (unsigned)key;
    const unsigned mhi = wave_min_u32(hi);
    const unsigned long long t = __ballot(hi == mhi);
    unsigned mlo;
    if (__popcll(t) > 1) mlo = wave_min_u32((hi == mhi) ? lo : 0xFFFFFFFFu);
    else                 mlo = (unsigned)__shfl((int)lo, __builtin_ctzll(t));
    return ((unsigned long long)mhi << 32) | mlo;
}

// order-preserving bijections double<->u64 (no NaNs in data)
__device__ __forceinline__ unsigned long long f64_key(double d) {
    unsigned long long b = (unsigned long long)__double_as_longlong(d);
    return b ^ ((unsigned long long)((long long)b >> 63) | 0x8000000000000000ULL);
}
__device__ __forceinline__ double key_f64(unsigned long long k) {
    unsigned long long b = (k & 0x8000000000000000ULL) ? (k ^ 0x8000000000000000ULL) : ~k;
    return __longlong_as_double((long long)b);
}

// ============================ Kernel A: Phase A =============================
__global__ __launch_bounds__(256) void phasea_kernel(
    const float* __restrict__ logits,   // (B,Q,NC)
    const float* __restrict__ pboxes,   // (B,Q,4)
    const int*   __restrict__ tlabels,  // (B,NT)
    const float* __restrict__ tboxes,   // (B,NT,4)
    float* __restrict__ cost,           // (B,NT,QQ) ws
    float* __restrict__ pm1,            // (B,NT,NTILE) ws
    float* __restrict__ pm2,            // (B,NT,NTILE) ws
    int*   __restrict__ pmj)            // (B,NT,NTILE) ws
{
    __shared__ float tile[64 * 93];
    __shared__ float s_pm[4 * 64], s_ps[4 * 64];
    __shared__ float s_tb[NT * 4];
    __shared__ int   s_tl[NT];
    __shared__ float s_scan[4][10][65]; // R25: per-wave cost staging, 65-pitch

    const int g   = blockIdx.x;
    const int b   = g / NTILE;
    const int tix = g % NTILE;
    const int tid = threadIdx.x;
    const int qq  = tid & 63;
    const int wv  = tid >> 6;           // 0..3

    const int q0 = tix * 64;
    const int nq = min(64, QQ - q0);   // 24 for the last tile
    const float* src = logits + ((size_t)b * QQ + q0) * NC;
    for (int idx = tid; idx < nq * NC; idx += 256) {
        const int r = idx / NC;
        tile[r * 93 + (idx - r * NC)] = src[idx];
    }
    for (int i = tid; i < NT * 4; i += 256) s_tb[i] = tboxes[b * NT * 4 + i];
    for (int i = tid; i < NT;     i += 256) s_tl[i] = tlabels[b * NT + i];
    __syncthreads();

    // 4-way parallel softmax stats; wave w owns cols [w*23, w*23+23).
    {
        const int c0 = wv * 23;
        const float* r = &tile[qq * 93];
        float pm = r[c0];
        #pragma unroll 11
        for (int c = 1; c < 23; ++c) pm = fmaxf(pm, r[c0 + c]);
        s_pm[wv * 64 + qq] = pm;
    }
    __syncthreads();
    {
        const int c0 = wv * 23;
        float* r = &tile[qq * 93];
        const float m = fmaxf(fmaxf(s_pm[qq], s_pm[64 + qq]),
                              fmaxf(s_pm[128 + qq], s_pm[192 + qq]));
        float sum = 0.f;
        #pragma unroll 11
        for (int c = 0; c < 23; ++c) {
            const float e = expf(r[c0 + c] - m);
            r[c0 + c] = e;                  // exp written back into tile
            sum += e;
        }
        s_ps[wv * 64 + qq] = sum;
    }
    __syncthreads();

    const bool valid = qq < nq;
    float px1 = 0.f, py1 = 0.f, px2 = 0.f, py2 = 0.f, pa = 0.f, inv_s = 1.f;
    if (valid) {
        const float* pb = pboxes + ((size_t)b * QQ + q0 + qq) * 4;
        px1 = pb[0]; py1 = pb[1]; px2 = pb[2]; py2 = pb[3];
        pa  = (px2 - px1) * (py2 - py1);
        const float s = (s_ps[qq] + s_ps[64 + qq]) + (s_ps[128 + qq] + s_ps[192 + qq]);
        inv_s = 1.f / s;
    }
    float* crow = cost + (size_t)b * NT * QQ + q0 + qq;

    // R25: two halves of 10 t's; stage costs in LDS, then 10-lane serial scan
    // replaces 2 dependent DPP wave-reduces per t.
    for (int h = 0; h < 2; ++h) {
        for (int tt = 0; tt < 10; ++tt) {
            const int t = wv * 20 + h * 10 + tt;
            float costv = INFINITY;
            if (valid) {
                const int lbl = s_tl[t];
                const float cc = -(tile[qq * 93 + lbl] * inv_s);  // exp precomputed
                const float tx1 = s_tb[t*4+0], ty1 = s_tb[t*4+1];
                const float tx2 = s_tb[t*4+2], ty2 = s_tb[t*4+3];
                const float cb = fabsf(px1-tx1) + fabsf(py1-ty1)
                               + fabsf(px2-tx2) + fabsf(py2-ty2);
                const float ta = (tx2 - tx1) * (ty2 - ty1);
                const float iw = fmaxf(fminf(px2, tx2) - fmaxf(px1, tx1), 0.f);
                const float ih = fmaxf(fminf(py2, ty2) - fmaxf(py1, ty1), 0.f);
                const float inter = iw * ih;
                const float uni   = pa + ta - inter;
                const float iou   = inter / uni;
                const float cw = fmaxf(fmaxf(px2, tx2) - fminf(px1, tx1), 0.f);
                const float ch = fmaxf(fmaxf(py2, ty2) - fminf(py1, ty1), 0.f);
                const float ac = cw * ch;
                const float giou = iou - (ac - uni) / ac;
                costv = (1.0f * cc + 5.0f * cb) + 2.0f * (-giou);
                crow[(size_t)t * QQ] = costv;
            }
            s_scan[wv][tt][qq] = costv;           // INF for invalid lanes
        }
        __syncthreads();    // stores visible (and compiler-ordered) for scan
        if (qq < 10) {
            const int t = wv * 20 + h * 10 + qq;
            const float* row = s_scan[wv][qq];
            float m1 = INFINITY, m2 = INFINITY; int j1 = 0;
            for (int j = 0; j < 64; ++j) {
                const float v = row[j];
                if (v < m1)      { m2 = m1; m1 = v; j1 = j; }  // first occurrence
                else if (v < m2) { m2 = v; }                   // dups kept
            }
            const size_t idx = ((size_t)b * NT + t) * NTILE + tix;
            pm1[idx] = m1; pm2[idx] = m2; pmj[idx] = q0 + j1;
        }
        __syncthreads();    // scans done before half 2 overwrites s_scan
    }
}

// ============================ Kernel B: solver (R23 verbatim) ===============
__global__ __launch_bounds__(256) void solver_kernel(
    const float* __restrict__ cost,     // (B,NT,QQ) ws
    const float* __restrict__ pm1,      // (B,NT,NTILE) ws
    const float* __restrict__ pm2,      // (B,NT,NTILE) ws
    const int*   __restrict__ pmj,      // (B,NT,NTILE) ws
    int* __restrict__ rows_out,         // (B,NT)
    int* __restrict__ cols_out)         // (B,NT)
{
    __shared__ double vA[QQ];
    __shared__ double u[NT];
    __shared__ double bidm1[NT], bidm2[NT];
    __shared__ int    bidj[NT], bidver[NT];
    __shared__ int    pA[QQ];
    __shared__ int    verA[QQ];
    __shared__ int    colrow[QQ];
    __shared__ int    assigned[NT];
    __shared__ int    plist[NT];
    __shared__ int    pcnt;
    __shared__ int    wayA[QQ];
    __shared__ int    c4r[NT];
    __shared__ int    djkA[NT];

    const int b   = blockIdx.x;
    const int tid = threadIdx.x;
    const int qq  = tid & 63;
    const int wv  = tid >> 6;           // 0..3
    const float* C = cost + (size_t)b * NT * QQ;

    // ---- init solver state ----
    for (int c = tid; c < QQ; c += NTHR) { pA[c] = -1; verA[c] = 0; vA[c] = 0.0; }
    if (tid < NT) { assigned[tid] = 0; bidver[tid] = 0; }
    __syncthreads();

    // ---- combine tile partials -> full-row bids (R6 verbatim) ----
    if (tid < NT) {
        const int t = tid;
        const float* p1 = pm1 + ((size_t)b * NT + t) * NTILE;
        const float* p2 = pm2 + ((size_t)b * NT + t) * NTILE;
        const int*   pj = pmj + ((size_t)b * NT + t) * NTILE;
        float m1 = INFINITY, m2 = INFINITY; int j1 = QQ;
        for (int k = 0; k < NTILE; ++k) {       // ascending => first-occurrence
            const float a1 = p1[k], a2 = p2[k];
            const int   aj = pj[k];
            if (a1 < m1) { m2 = fminf(m1, a2); m1 = a1; j1 = aj; }
            else         { m2 = fminf(m2, a1); }
        }
        bidm1[t] = (double)m1; bidm2[t] = (double)m2; bidj[t] = j1;
        u[t] = (double)m1;      // feasible: keys only increase afterwards
    }
    __syncthreads();

    // ================= Jacobi parallel auction (R16 structure) =============
    int prev_np = 0x7fffffff, stall = 0;
    for (int round = 0; round < MAXROUNDS; ++round) {
        for (int c = tid; c < QQ; c += NTHR) colrow[c] = 0x7fffffff;
        if (tid == 0) pcnt = 0;
        __syncthreads();
        if (tid < NT && !assigned[tid]) {
            const int j = bidj[tid];
            if (bidver[tid] == verA[j]) atomicMin(&colrow[j], tid);
        }
        __syncthreads();
        if (tid < NT && !assigned[tid]) {
            const int i = tid, j = bidj[i];
            if (bidver[i] == verA[j] && colrow[j] == i) {
                const double m1 = bidm1[i], m2 = bidm2[i];
                const int prev = pA[j];
                pA[j] = i;
                verA[j] = verA[j] + 1;
                vA[j] -= (m2 - m1);          // v only decreases (diff >= 0)
                u[i] = m2;
                assigned[i] = 1;
                if (prev >= 0) assigned[prev] = 0;
            }
        }
        __syncthreads();
        if (tid < NT && !assigned[tid]) { const int k = atomicAdd(&pcnt, 1); plist[k] = tid; }
        __syncthreads();
        const int np = pcnt;
        if (np == 0) break;
        if (np >= prev_np) { if (++stall >= STALLCAP) break; }
        else               { stall = 0; }
        prev_np = np;
        for (int idx = wv; idx < np; idx += NWAVE) {
            const int i = plist[idx];
            const float* rp = C + (size_t)i * QQ;
            float rowv[SLOTS];
            #pragma unroll
            for (int k = 0; k < SLOTS; ++k) { const int c = qq + 64*k; rowv[k] = (c < QQ) ? rp[c] : 0.f; }
            double m1 = INFINITY, m2 = INFINITY; int j1 = QQ;
            #pragma unroll
            for (int k = 0; k < SLOTS; ++k) {
                const int c = qq + 64 * k;
                if (c < QQ) {
                    const double key = (double)rowv[k] - vA[c];
                    if (key < m1)      { m2 = m1; m1 = key; j1 = c; }
                    else if (key < m2) { m2 = key; }
                }
            }
            int winlane;
            const unsigned long long kminv = wave_min_key64(f64_key(m1), &winlane);
            // global 2nd-min = min over (winner's m2, everyone else's m1)
            const unsigned long long c2 = (qq == winlane) ? f64_key(m2) : f64_key(m1);
            const unsigned long long k2minv = wave_min_key64_val(c2);
            const int jwin = __shfl(j1, winlane);
            if (qq == 0) {
                bidm1[i] = key_f64(kminv); bidm2[i] = key_f64(k2minv); bidj[i] = jwin;
                bidver[i] = verA[jwin];
                u[i] = key_f64(kminv);       // feasible forever (v only dec.)
            }
        }
        __syncthreads();
    }

    if (wv != 0) return;   // ============ wave 0 only below; no barriers ====
    const int lane = qq;

    // collect drained rows (uniform control flow)
    int nd = 0;
    for (int i = 0; i < NT; ++i) {
        if (!assigned[i]) { if (lane == 0) djkA[nd] = i; ++nd; }
    }

    double v_[SLOTS], minv_[SLOTS];
    int p_[SLOTS];
    #pragma unroll
    for (int k = 0; k < SLOTS; ++k) {
        const int c = lane + 64 * k;
        v_[k] = (c < QQ) ? vA[c] : 0.0;
        p_[k] = (c < QQ) ? pA[c] : -1;
    }

    // ================= Dijkstra SAP (exact, R16 structure) =================
    float rowv[SLOTS];
    for (int ii = 0; ii < nd; ++ii) {
        const int i = djkA[ii];
        #pragma unroll
        for (int k = 0; k < SLOTS; ++k) minv_[k] = INFINITY;
        unsigned usedm = 0;
        int j0 = -1;
        double ui0 = u[i];
        {
            const float* rp = C + (size_t)i * QQ;
            #pragma unroll
            for (int k = 0; k < SLOTS; ++k) { const int c = lane + 64*k; rowv[k] = (c < QQ) ? rp[c] : 0.f; }
        }
        int j1, i1;

        for (;;) {
            if (j0 >= 0 && (j0 & 63) == lane) usedm |= 1u << (j0 >> 6);

            double bestv = INFINITY; int bestc = QQ;
            #pragma unroll
            for (int k = 0; k < SLOTS; ++k) {
                const int c = lane + 64 * k;
                if (c < QQ && !((usedm >> k) & 1u)) {
                    const double cur = ((double)rowv[k] - ui0) - v_[k];
                    if (cur < minv_[k]) { minv_[k] = cur; wayA[c] = j0; }
                    if (minv_[k] < bestv) { bestv = minv_[k]; bestc = c; }
                }
            }
            int winlane;
            const unsigned long long kminv = wave_min_key64(f64_key(bestv), &winlane);
            const double delta = key_f64(kminv);
            j1 = __shfl(bestc, winlane);

            {   // i1 = p[j1] via register select + shuffle
                const int slot = j1 >> 6, lj = j1 & 63;
                int myp = p_[0];
                #pragma unroll
                for (int k = 1; k < SLOTS; ++k) if (slot == k) myp = p_[k];
                i1 = __shfl(myp, lj);
            }

            double ui_next = 0.0;
            float rown[SLOTS];
            if (i1 >= 0) {      // prefetch next row (not in tree -> u stable)
                ui_next = u[i1];
                const float* rp = C + (size_t)i1 * QQ;
                #pragma unroll
                for (int k = 0; k < SLOTS; ++k) { const int c = lane + 64*k; rown[k] = (c < QQ) ? rp[c] : 0.f; }
            }

            #pragma unroll
            for (int k = 0; k < SLOTS; ++k) {
                const int c = lane + 64 * k;
                if (c < QQ) {
                    if ((usedm >> k) & 1u) { v_[k] -= delta; u[p_[k]] += delta; }
                    else                     minv_[k] -= delta;
                }
            }
            if (lane == 0) u[i] += delta;

            j0 = j1;
            if (i1 < 0) break;
            ui0 = ui_next;
            #pragma unroll
            for (int k = 0; k < SLOTS; ++k) rowv[k] = rown[k];
        }

        if (lane == 0) {        // augment along way chain
            int jj = j1;
            while (jj >= 0) {
                const int pr = wayA[jj];
                pA[jj] = (pr < 0) ? i : pA[pr];
                jj = pr;
            }
        }
        #pragma unroll
        for (int k = 0; k < SLOTS; ++k) {
            const int c = lane + 64 * k;
            p_[k] = (c < QQ) ? pA[c] : -1;
        }
    }

    // ---- emit in increasing query order (== reference's stable argsort) ----
    #pragma unroll
    for (int k = 0; k < SLOTS; ++k) {
        const int c = lane + 64 * k;
        if (c < QQ) { const int t = pA[c]; if (t >= 0) c4r[t] = c; }
    }
    for (int t = lane; t < NT; t += 64) {
        const int c = c4r[t];
        int rank = 0;
        for (int t2 = 0; t2 < NT; ++t2) rank += (c4r[t2] < c) ? 1 : 0;
        rows_out[b * NT + rank] = c;
        cols_out[b * NT + rank] = t;
    }
}

extern "C" void kernel_launch(void* const* d_in, const int* in_sizes, int n_in,
                              void* d_out, int out_size, void* d_ws, size_t ws_size,
                              hipStream_t stream) {
    (void)in_sizes; (void)n_in; (void)out_size; (void)ws_size;
    const float* logits  = (const float*)d_in[0];
    const float* pboxes  = (const float*)d_in[1];
    const int*   tlabels = (const int*)d_in[2];
    const float* tboxes  = (const float*)d_in[3];
    float* cost = (float*)d_ws;                          // 12,288,000 B
    float* pm1  = cost + (size_t)BB * NT * QQ;           // +204,800 B
    float* pm2  = pm1  + (size_t)BB * NT * NTILE;        // +204,800 B
    int*   pmj  = (int*)(pm2 + (size_t)BB * NT * NTILE); // +204,800 B
    int*   out  = (int*)d_out;

    phasea_kernel<<<dim3(BB * NTILE), NTHR, 0, stream>>>(
        logits, pboxes, tlabels, tboxes, cost, pm1, pm2, pmj);
    solver_kernel<<<dim3(BB), NTHR, 0, stream>>>(
        cost, pm1, pm2, pmj, out, out + BB * NT);
}

// Round 12
// 108.643 us; speedup vs baseline: 1.0017x; 1.0008x over previous
//
#include <hip/hip_runtime.h>
#include <math.h>

#define BB 64
#define QQ 600
#define NT 80
#define NC 92
#define SLOTS 10     // ceil(600/64)
#define NTILE 10     // 64-query tiles per batch
#define NTHR 256
#define NWAVE 4
#define MAXROUNDS 16 // Jacobi auction cap
#define STALLCAP 3   // break auction after 3 rounds with no new assignment

// ---------------------------------------------------------------------------
// R26 = R23 VERBATIM (best measured: 107.6us). Final lock-in revert.
// Session summary: wins were structural — R16 DPP reductions (72->64us),
// R19 Phase-A softmax restructure (64->62), R22/R23 kernel split (-12us,
// occupancy + handshake removal). Four consecutive micro-opt nulls
// (R20 L2-prefetch, R21 two-phase reduce, R24 dist-form drain, R25 LDS-scan
// Phase A) establish that the solver's latency-chain components mutually
// overlap at this occupancy — no single chain is exposed. Remaining bench
// time: ~42us harness workspace re-poison (at 80% HBM roofline, not
// kernel-controllable) + ~50us latency-bound batch-parallel Hungarian
// (VALUBusy ~4%, Occ ~8%) + launch overhead.
//   kernel A (640 blocks): Phase A -> cost + pm1/pm2/pmj.
//   kernel B (64 blocks):  solver (init/combine/auction/drain/emit).
// Same-stream ordering is the cross-XCD coherence point (no handshake).
// ---------------------------------------------------------------------------

template <int CTRL>
__device__ __forceinline__ int dppi(int x) {
    return __builtin_amdgcn_update_dpp(x, x, CTRL, 0xF, 0xF, false);
}

// full-wave (64-lane) min of u32: 4x row_ror DPP (VALU) + xor16 swizzle + xor32
__device__ __forceinline__ unsigned wave_min_u32(unsigned x) {
    unsigned y;
    y = (unsigned)dppi<0x121>((int)x); x = x < y ? x : y;   // ror1
    y = (unsigned)dppi<0x122>((int)x); x = x < y ? x : y;   // ror2
    y = (unsigned)dppi<0x124>((int)x); x = x < y ? x : y;   // ror4
    y = (unsigned)dppi<0x128>((int)x); x = x < y ? x : y;   // ror8 -> row(16) min
    y = (unsigned)__builtin_amdgcn_ds_swizzle((int)x, 0x401F); x = x < y ? x : y; // xor16
    y = (unsigned)__shfl_xor((int)x, 32); x = x < y ? x : y;                      // xor32
    return x;
}

// exact 64-lane min of a u64 sortable key, two-phase (hi then lo).
// Returns min key; *winlane = lowest lane holding it (old tie semantics).
__device__ __forceinline__ unsigned long long wave_min_key64(
        unsigned long long key, int* winlane) {
    const unsigned hi = (unsigned)(key >> 32), lo = (unsigned)key;
    const unsigned mhi = wave_min_u32(hi);
    unsigned long long t = __ballot(hi == mhi);
    unsigned mlo;
    if (__popcll(t) > 1) {          // wave-uniform branch (t uniform)
        mlo = wave_min_u32((hi == mhi) ? lo : 0xFFFFFFFFu);
        t = __ballot(hi == mhi && lo == mlo);
    } else {
        mlo = (unsigned)__shfl((int)lo, __builtin_ctzll(t));
    }
    *winlane = __builtin_ctzll(t);
    return ((unsigned long long)mhi << 32) | mlo;
}

// min-value-only variant (no winlane needed)
__device__ __forceinline__ unsigned long long wave_min_key64_val(
        unsigned long long key) {
    const unsigned hi = (unsigned)(key >> 32), lo = (unsigned)key;
    const unsigned mhi = wave_min_u32(hi);
    const unsigned long long t = __ballot(hi == mhi);
    unsigned mlo;
    if (__popcll(t) > 1) mlo = wave_min_u32((hi == mhi) ? lo : 0xFFFFFFFFu);
    else                 mlo = (unsigned)__shfl((int)lo, __builtin_ctzll(t));
    return ((unsigned long long)mhi << 32) | mlo;
}

// order-preserving bijections float<->u32, double<->u64 (no NaNs in data)
__device__ __forceinline__ unsigned f32_key(float f) {
    unsigned b = __float_as_uint(f);
    return b ^ ((unsigned)((int)b >> 31) | 0x80000000u);
}
__device__ __forceinline__ float key_f32(unsigned k) {
    unsigned b = (k & 0x80000000u) ? (k ^ 0x80000000u) : ~k;
    return __uint_as_float(b);
}
__device__ __forceinline__ unsigned long long f64_key(double d) {
    unsigned long long b = (unsigned long long)__double_as_longlong(d);
    return b ^ ((unsigned long long)((long long)b >> 63) | 0x8000000000000000ULL);
}
__device__ __forceinline__ double key_f64(unsigned long long k) {
    unsigned long long b = (k & 0x8000000000000000ULL) ? (k ^ 0x8000000000000000ULL) : ~k;
    return __longlong_as_double((long long)b);
}

// ============================ Kernel A: Phase A =============================
__global__ __launch_bounds__(256) void phasea_kernel(
    const float* __restrict__ logits,   // (B,Q,NC)
    const float* __restrict__ pboxes,   // (B,Q,4)
    const int*   __restrict__ tlabels,  // (B,NT)
    const float* __restrict__ tboxes,   // (B,NT,4)
    float* __restrict__ cost,           // (B,NT,QQ) ws
    float* __restrict__ pm1,            // (B,NT,NTILE) ws
    float* __restrict__ pm2,            // (B,NT,NTILE) ws
    int*   __restrict__ pmj)            // (B,NT,NTILE) ws
{
    __shared__ float tile[64 * 93];
    __shared__ float s_pm[4 * 64], s_ps[4 * 64];
    __shared__ float s_tb[NT * 4];
    __shared__ int   s_tl[NT];

    const int g   = blockIdx.x;
    const int b   = g / NTILE;
    const int tix = g % NTILE;
    const int tid = threadIdx.x;
    const int qq  = tid & 63;
    const int wv  = tid >> 6;           // 0..3

    const int q0 = tix * 64;
    const int nq = min(64, QQ - q0);   // 24 for the last tile
    const float* src = logits + ((size_t)b * QQ + q0) * NC;
    for (int idx = tid; idx < nq * NC; idx += 256) {
        const int r = idx / NC;
        tile[r * 93 + (idx - r * NC)] = src[idx];
    }
    for (int i = tid; i < NT * 4; i += 256) s_tb[i] = tboxes[b * NT * 4 + i];
    for (int i = tid; i < NT;     i += 256) s_tl[i] = tlabels[b * NT + i];
    __syncthreads();

    // 4-way parallel softmax stats; wave w owns cols [w*23, w*23+23).
    {
        const int c0 = wv * 23;
        const float* r = &tile[qq * 93];
        float pm = r[c0];
        #pragma unroll 11
        for (int c = 1; c < 23; ++c) pm = fmaxf(pm, r[c0 + c]);
        s_pm[wv * 64 + qq] = pm;
    }
    __syncthreads();
    {
        const int c0 = wv * 23;
        float* r = &tile[qq * 93];
        const float m = fmaxf(fmaxf(s_pm[qq], s_pm[64 + qq]),
                              fmaxf(s_pm[128 + qq], s_pm[192 + qq]));
        float sum = 0.f;
        #pragma unroll 11
        for (int c = 0; c < 23; ++c) {
            const float e = expf(r[c0 + c] - m);
            r[c0 + c] = e;                  // exp written back into tile
            sum += e;
        }
        s_ps[wv * 64 + qq] = sum;
    }
    __syncthreads();

    const bool valid = qq < nq;
    float px1 = 0.f, py1 = 0.f, px2 = 0.f, py2 = 0.f, pa = 0.f, inv_s = 1.f;
    if (valid) {
        const float* pb = pboxes + ((size_t)b * QQ + q0 + qq) * 4;
        px1 = pb[0]; py1 = pb[1]; px2 = pb[2]; py2 = pb[3];
        pa  = (px2 - px1) * (py2 - py1);
        const float s = (s_ps[qq] + s_ps[64 + qq]) + (s_ps[128 + qq] + s_ps[192 + qq]);
        inv_s = 1.f / s;
    }
    float* crow = cost + (size_t)b * NT * QQ + q0 + qq;

    for (int tt = 0; tt < 20; ++tt) {
        const int t = wv * 20 + tt;
        float costv = INFINITY;
        if (valid) {
            const int lbl = s_tl[t];
            const float cc = -(tile[qq * 93 + lbl] * inv_s);  // exp precomputed
            const float tx1 = s_tb[t*4+0], ty1 = s_tb[t*4+1];
            const float tx2 = s_tb[t*4+2], ty2 = s_tb[t*4+3];
            const float cb = fabsf(px1-tx1) + fabsf(py1-ty1)
                           + fabsf(px2-tx2) + fabsf(py2-ty2);
            const float ta = (tx2 - tx1) * (ty2 - ty1);
            const float iw = fmaxf(fminf(px2, tx2) - fmaxf(px1, tx1), 0.f);
            const float ih = fmaxf(fminf(py2, ty2) - fmaxf(py1, ty1), 0.f);
            const float inter = iw * ih;
            const float uni   = pa + ta - inter;
            const float iou   = inter / uni;
            const float cw = fmaxf(fmaxf(px2, tx2) - fminf(px1, tx1), 0.f);
            const float ch = fmaxf(fmaxf(py2, ty2) - fminf(py1, ty1), 0.f);
            const float ac = cw * ch;
            const float giou = iou - (ac - uni) / ac;
            costv = (1.0f * cc + 5.0f * cb) + 2.0f * (-giou);
            crow[(size_t)t * QQ] = costv;
        }
        // DPP min-reduce on sortable keys + ballot argmin (R16-validated)
        const unsigned key  = f32_key(costv);          // INF for invalid lanes
        const unsigned kmin = wave_min_u32(key);
        const unsigned long long tied = __ballot(key == kmin);
        const int winlane = __builtin_ctzll(tied);
        const unsigned cand = (qq == winlane) ? 0xFFFFFFFFu : key;
        const unsigned k2   = wave_min_u32(cand);      // 2nd-min (dups kept)
        if (qq == 0) {
            const size_t idx = ((size_t)b * NT + t) * NTILE + tix;
            pm1[idx] = key_f32(kmin); pm2[idx] = key_f32(k2);
            pmj[idx] = q0 + winlane;
        }
    }
}

// ============================ Kernel B: solver ==============================
__global__ __launch_bounds__(256) void solver_kernel(
    const float* __restrict__ cost,     // (B,NT,QQ) ws
    const float* __restrict__ pm1,      // (B,NT,NTILE) ws
    const float* __restrict__ pm2,      // (B,NT,NTILE) ws
    const int*   __restrict__ pmj,      // (B,NT,NTILE) ws
    int* __restrict__ rows_out,         // (B,NT)
    int* __restrict__ cols_out)         // (B,NT)
{
    __shared__ double vA[QQ];
    __shared__ double u[NT];
    __shared__ double bidm1[NT], bidm2[NT];
    __shared__ int    bidj[NT], bidver[NT];
    __shared__ int    pA[QQ];
    __shared__ int    verA[QQ];
    __shared__ int    colrow[QQ];
    __shared__ int    assigned[NT];
    __shared__ int    plist[NT];
    __shared__ int    pcnt;
    __shared__ int    wayA[QQ];
    __shared__ int    c4r[NT];
    __shared__ int    djkA[NT];

    const int b   = blockIdx.x;
    const int tid = threadIdx.x;
    const int qq  = tid & 63;
    const int wv  = tid >> 6;           // 0..3
    const float* C = cost + (size_t)b * NT * QQ;

    // ---- init solver state ----
    for (int c = tid; c < QQ; c += NTHR) { pA[c] = -1; verA[c] = 0; vA[c] = 0.0; }
    if (tid < NT) { assigned[tid] = 0; bidver[tid] = 0; }
    __syncthreads();

    // ---- combine tile partials -> full-row bids (R6 verbatim) ----
    if (tid < NT) {
        const int t = tid;
        const float* p1 = pm1 + ((size_t)b * NT + t) * NTILE;
        const float* p2 = pm2 + ((size_t)b * NT + t) * NTILE;
        const int*   pj = pmj + ((size_t)b * NT + t) * NTILE;
        float m1 = INFINITY, m2 = INFINITY; int j1 = QQ;
        for (int k = 0; k < NTILE; ++k) {       // ascending => first-occurrence
            const float a1 = p1[k], a2 = p2[k];
            const int   aj = pj[k];
            if (a1 < m1) { m2 = fminf(m1, a2); m1 = a1; j1 = aj; }
            else         { m2 = fminf(m2, a1); }
        }
        bidm1[t] = (double)m1; bidm2[t] = (double)m2; bidj[t] = j1;
        u[t] = (double)m1;      // feasible: keys only increase afterwards
    }
    __syncthreads();

    // ================= Jacobi parallel auction (R16 structure) =============
    int prev_np = 0x7fffffff, stall = 0;
    for (int round = 0; round < MAXROUNDS; ++round) {
        for (int c = tid; c < QQ; c += NTHR) colrow[c] = 0x7fffffff;
        if (tid == 0) pcnt = 0;
        __syncthreads();
        if (tid < NT && !assigned[tid]) {
            const int j = bidj[tid];
            if (bidver[tid] == verA[j]) atomicMin(&colrow[j], tid);
        }
        __syncthreads();
        if (tid < NT && !assigned[tid]) {
            const int i = tid, j = bidj[i];
            if (bidver[i] == verA[j] && colrow[j] == i) {
                const double m1 = bidm1[i], m2 = bidm2[i];
                const int prev = pA[j];
                pA[j] = i;
                verA[j] = verA[j] + 1;
                vA[j] -= (m2 - m1);          // v only decreases (diff >= 0)
                u[i] = m2;
                assigned[i] = 1;
                if (prev >= 0) assigned[prev] = 0;
            }
        }
        __syncthreads();
        if (tid < NT && !assigned[tid]) { const int k = atomicAdd(&pcnt, 1); plist[k] = tid; }
        __syncthreads();
        const int np = pcnt;
        if (np == 0) break;
        if (np >= prev_np) { if (++stall >= STALLCAP) break; }
        else               { stall = 0; }
        prev_np = np;
        for (int idx = wv; idx < np; idx += NWAVE) {
            const int i = plist[idx];
            const float* rp = C + (size_t)i * QQ;
            float rowv[SLOTS];
            #pragma unroll
            for (int k = 0; k < SLOTS; ++k) { const int c = qq + 64*k; rowv[k] = (c < QQ) ? rp[c] : 0.f; }
            double m1 = INFINITY, m2 = INFINITY; int j1 = QQ;
            #pragma unroll
            for (int k = 0; k < SLOTS; ++k) {
                const int c = qq + 64 * k;
                if (c < QQ) {
                    const double key = (double)rowv[k] - vA[c];
                    if (key < m1)      { m2 = m1; m1 = key; j1 = c; }
                    else if (key < m2) { m2 = key; }
                }
            }
            int winlane;
            const unsigned long long kminv = wave_min_key64(f64_key(m1), &winlane);
            // global 2nd-min = min over (winner's m2, everyone else's m1)
            const unsigned long long c2 = (qq == winlane) ? f64_key(m2) : f64_key(m1);
            const unsigned long long k2minv = wave_min_key64_val(c2);
            const int jwin = __shfl(j1, winlane);
            if (qq == 0) {
                bidm1[i] = key_f64(kminv); bidm2[i] = key_f64(k2minv); bidj[i] = jwin;
                bidver[i] = verA[jwin];
                u[i] = key_f64(kminv);       // feasible forever (v only dec.)
            }
        }
        __syncthreads();
    }

    if (wv != 0) return;   // ============ wave 0 only below; no barriers ====
    const int lane = qq;

    // collect drained rows (uniform control flow)
    int nd = 0;
    for (int i = 0; i < NT; ++i) {
        if (!assigned[i]) { if (lane == 0) djkA[nd] = i; ++nd; }
    }

    double v_[SLOTS], minv_[SLOTS];
    int p_[SLOTS];
    #pragma unroll
    for (int k = 0; k < SLOTS; ++k) {
        const int c = lane + 64 * k;
        v_[k] = (c < QQ) ? vA[c] : 0.0;
        p_[k] = (c < QQ) ? pA[c] : -1;
    }

    // ================= Dijkstra SAP (exact, R16 structure) =================
    float rowv[SLOTS];
    for (int ii = 0; ii < nd; ++ii) {
        const int i = djkA[ii];
        #pragma unroll
        for (int k = 0; k < SLOTS; ++k) minv_[k] = INFINITY;
        unsigned usedm = 0;
        int j0 = -1;
        double ui0 = u[i];
        {
            const float* rp = C + (size_t)i * QQ;
            #pragma unroll
            for (int k = 0; k < SLOTS; ++k) { const int c = lane + 64*k; rowv[k] = (c < QQ) ? rp[c] : 0.f; }
        }
        int j1, i1;

        for (;;) {
            if (j0 >= 0 && (j0 & 63) == lane) usedm |= 1u << (j0 >> 6);

            double bestv = INFINITY; int bestc = QQ;
            #pragma unroll
            for (int k = 0; k < SLOTS; ++k) {
                const int c = lane + 64 * k;
                if (c < QQ && !((usedm >> k) & 1u)) {
                    const double cur = ((double)rowv[k] - ui0) - v_[k];
                    if (cur < minv_[k]) { minv_[k] = cur; wayA[c] = j0; }
                    if (minv_[k] < bestv) { bestv = minv_[k]; bestc = c; }
                }
            }
            int winlane;
            const unsigned long long kminv = wave_min_key64(f64_key(bestv), &winlane);
            const double delta = key_f64(kminv);
            j1 = __shfl(bestc, winlane);

            {   // i1 = p[j1] via register select + shuffle
                const int slot = j1 >> 6, lj = j1 & 63;
                int myp = p_[0];
                #pragma unroll
                for (int k = 1; k < SLOTS; ++k) if (slot == k) myp = p_[k];
                i1 = __shfl(myp, lj);
            }

            double ui_next = 0.0;
            float rown[SLOTS];
            if (i1 >= 0) {      // prefetch next row (not in tree -> u stable)
                ui_next = u[i1];
                const float* rp = C + (size_t)i1 * QQ;
                #pragma unroll
                for (int k = 0; k < SLOTS; ++k) { const int c = lane + 64*k; rown[k] = (c < QQ) ? rp[c] : 0.f; }
            }

            #pragma unroll
            for (int k = 0; k < SLOTS; ++k) {
                const int c = lane + 64 * k;
                if (c < QQ) {
                    if ((usedm >> k) & 1u) { v_[k] -= delta; u[p_[k]] += delta; }
                    else                     minv_[k] -= delta;
                }
            }
            if (lane == 0) u[i] += delta;

            j0 = j1;
            if (i1 < 0) break;
            ui0 = ui_next;
            #pragma unroll
            for (int k = 0; k < SLOTS; ++k) rowv[k] = rown[k];
        }

        if (lane == 0) {        // augment along way chain
            int jj = j1;
            while (jj >= 0) {
                const int pr = wayA[jj];
                pA[jj] = (pr < 0) ? i : pA[pr];
                jj = pr;
            }
        }
        #pragma unroll
        for (int k = 0; k < SLOTS; ++k) {
            const int c = lane + 64 * k;
            p_[k] = (c < QQ) ? pA[c] : -1;
        }
    }

    // ---- emit in increasing query order (== reference's stable argsort) ----
    #pragma unroll
    for (int k = 0; k < SLOTS; ++k) {
        const int c = lane + 64 * k;
        if (c < QQ) { const int t = pA[c]; if (t >= 0) c4r[t] = c; }
    }
    for (int t = lane; t < NT; t += 64) {
        const int c = c4r[t];
        int rank = 0;
        for (int t2 = 0; t2 < NT; ++t2) rank += (c4r[t2] < c) ? 1 : 0;
        rows_out[b * NT + rank] = c;
        cols_out[b * NT + rank] = t;
    }
}

extern "C" void kernel_launch(void* const* d_in, const int* in_sizes, int n_in,
                              void* d_out, int out_size, void* d_ws, size_t ws_size,
                              hipStream_t stream) {
    (void)in_sizes; (void)n_in; (void)out_size; (void)ws_size;
    const float* logits  = (const float*)d_in[0];
    const float* pboxes  = (const float*)d_in[1];
    const int*   tlabels = (const int*)d_in[2];
    const float* tboxes  = (const float*)d_in[3];
    float* cost = (float*)d_ws;                          // 12,288,000 B
    float* pm1  = cost + (size_t)BB * NT * QQ;           // +204,800 B
    float* pm2  = pm1  + (size_t)BB * NT * NTILE;        // +204,800 B
    int*   pmj  = (int*)(pm2 + (size_t)BB * NT * NTILE); // +204,800 B
    int*   out  = (int*)d_out;

    phasea_kernel<<<dim3(BB * NTILE), NTHR, 0, stream>>>(
        logits, pboxes, tlabels, tboxes, cost, pm1, pm2, pmj);
    solver_kernel<<<dim3(BB), NTHR, 0, stream>>>(
        cost, pm1, pm2, pmj, out, out + BB * NT);
}